// Round 10
// baseline (1815.752 us; speedup 1.0000x reference)
//
#include <hip/hip_runtime.h>
#include <hip/hip_bf16.h>

#define NB 16
#define NP 4096
#define MS 1024
#define NN 65536
#define FIN 64
#define FOUT 128
#define KNN_MARGIN 0.25f

typedef __attribute__((ext_vector_type(8))) short short8;
typedef __attribute__((ext_vector_type(4))) float f32x4;
typedef __attribute__((ext_vector_type(2))) float f32x2;

// DPP cumulative-max step (VALU pipe, no LDS)
template <int CTRL>
__device__ __forceinline__ unsigned long long dpp_max_step(unsigned long long k) {
    unsigned lo = (unsigned)k, hi = (unsigned)(k >> 32);
    unsigned plo = (unsigned)__builtin_amdgcn_update_dpp(0, (int)lo, CTRL, 0xf, 0xf, true);
    unsigned phi = (unsigned)__builtin_amdgcn_update_dpp(0, (int)hi, CTRL, 0xf, 0xf, true);
    unsigned long long pk = ((unsigned long long)phi << 32) | plo;   // invalid lanes -> 0 (identity)
    return pk > k ? pk : k;
}

__device__ __forceinline__ unsigned short bf16_rn(float v) {
    unsigned u = __float_as_uint(v);
    unsigned r = u + 0x7FFF + ((u >> 16) & 1);
    return (unsigned short)(r >> 16);
}

// ---------------------------------------------------------------- mega: FPS || (GEMM+split -> knn -> refine)
__global__ __launch_bounds__(512, 4) void mega_kernel(
        const float* __restrict__ pos, const float* __restrict__ feat,
        const float* __restrict__ W, const float* __restrict__ bias,
        const float* __restrict__ gamma, const float* __restrict__ beta,
        int* __restrict__ fps_idx, float* __restrict__ xnorm,
        unsigned short* __restrict__ Xhi, unsigned short* __restrict__ Xlo,
        __hip_bfloat16* __restrict__ hout, float* __restrict__ gsum, float* __restrict__ gsq,
        float* __restrict__ acoef, float* __restrict__ ccoef,
        unsigned short* __restrict__ cand, int* flags,
        float* __restrict__ out_feat, float* __restrict__ out_pos, float* __restrict__ out_batch) {
    __shared__ float smem[13344];
    int* fps_flag = flags;            // [16][16]
    int* splitc   = flags + 256;      // [16]
    int* gemmc    = flags + 272;      // [1]
    int* knnc     = flags + 288;      // [16]
    int* bnflag   = flags + 304;      // [1]
    const int t = threadIdx.x;
    const int b = blockIdx.x;

    if (b < 16) {
        // ================ FPS: 512 thr x 8 pts, packed-f32 phase A (R9-validated) =========
        float* plds = smem;                                   // 12288 floats
        int* idxL = (int*)(smem + 12288);                     // 1024 ints
        unsigned long long* rk = (unsigned long long*)(smem + 13312);  // 16 u64
        const float* pb = pos + (size_t)b * NP * 3;
#pragma unroll
        for (int i = 0; i < 24; i++) { int id = t + 512 * i; plds[id] = pb[id]; }
        __syncthreads();
        f32x2 px2[4], py2[4], pz2[4], dist2[4];
#pragma unroll
        for (int j = 0; j < 4; j++) {
            int pA = t + 512 * j, pB = t + 512 * (j + 4);
            px2[j] = (f32x2){plds[pA * 3 + 0], plds[pB * 3 + 0]};
            py2[j] = (f32x2){plds[pA * 3 + 1], plds[pB * 3 + 1]};
            pz2[j] = (f32x2){plds[pA * 3 + 2], plds[pB * 3 + 2]};
            dist2[j] = (f32x2){INFINITY, INFINITY};
        }
        float lx = plds[0], ly = plds[1], lz = plds[2];
        if (t == 0) idxL[0] = 0;
        const int ln = t & 63, wv = t >> 6;   // 8 waves
        for (int m = 1; m < MS; m++) {
            f32x2 l2x = {lx, lx}, l2y = {ly, ly}, l2z = {lz, lz};
#pragma unroll
            for (int j = 0; j < 4; j++) {
                f32x2 dx = px2[j] - l2x, dy = py2[j] - l2y, dz = pz2[j] - l2z;
                f32x2 d = __builtin_elementwise_fma(dx, dx,
                              __builtin_elementwise_fma(dy, dy, dz * dz));
                dist2[j] = __builtin_elementwise_min(dist2[j], d);
            }
            float d1[4]; int i1[4];
#pragma unroll
            for (int j = 0; j < 4; j++) {
                bool g = dist2[j].y > dist2[j].x;
                d1[j] = g ? dist2[j].y : dist2[j].x; i1[j] = g ? (j + 4) : j;
            }
            float d2[2]; int i2[2];
#pragma unroll
            for (int i = 0; i < 2; i++) {
                bool g = d1[i + 2] > d1[i];
                d2[i] = g ? d1[i + 2] : d1[i]; i2[i] = g ? i1[i + 2] : i1[i];
            }
            bool g3 = d2[1] > d2[0];
            float bd = g3 ? d2[1] : d2[0];
            int bi = g3 ? i2[1] : i2[0];
            int bp = t + (bi << 9);
            unsigned long long key =
                ((unsigned long long)__float_as_uint(bd) << 32) | (unsigned)(~bp);
            key = dpp_max_step<0x111>(key);
            key = dpp_max_step<0x112>(key);
            key = dpp_max_step<0x114>(key);
            key = dpp_max_step<0x118>(key);
            key = dpp_max_step<0x142>(key);
            key = dpp_max_step<0x143>(key);
            const int par = (m & 1) * 8;
            if (ln == 63) rk[par + wv] = key;
            __syncthreads();
            unsigned long long k0 = rk[par + 0], k1 = rk[par + 1];
            unsigned long long k2 = rk[par + 2], k3 = rk[par + 3];
            unsigned long long k4 = rk[par + 4], k5 = rk[par + 5];
            unsigned long long k6 = rk[par + 6], k7 = rk[par + 7];
            unsigned long long ka = k0 > k1 ? k0 : k1;
            unsigned long long kb = k2 > k3 ? k2 : k3;
            unsigned long long kc = k4 > k5 ? k4 : k5;
            unsigned long long kd = k6 > k7 ? k6 : k7;
            ka = ka > kb ? ka : kb;
            kc = kc > kd ? kc : kd;
            unsigned long long kw = ka > kc ? ka : kc;
            bp = (int)(~(unsigned)kw) & 0xFFF;
            lx = plds[bp * 3 + 0]; ly = plds[bp * 3 + 1]; lz = plds[bp * 3 + 2];
            if (t == 0) idxL[m] = bp;
            if ((m & 63) == 63) {   // qgroup complete: publish indices + release flag
                __syncthreads();
                const int g = m >> 6;
                if (t < 64) fps_idx[(size_t)b * MS + g * 64 + t] = idxL[g * 64 + t];
                __threadfence();
                __syncthreads();
                if (t == 0)
                    __hip_atomic_store(&fps_flag[b * 16 + g], 1, __ATOMIC_RELEASE,
                                       __HIP_MEMORY_SCOPE_AGENT);
            }
        }
        __syncthreads();
        for (int m = t; m < MS; m += 512) {
            int ix = idxL[m];
            size_t o = (size_t)b * MS + m;
            out_pos[o * 3 + 0] = plds[ix * 3 + 0];
            out_pos[o * 3 + 1] = plds[ix * 3 + 1];
            out_pos[o * 3 + 2] = plds[ix * 3 + 2];
            out_batch[o] = (float)b;
        }
        return;
    }

    // ================ worker block: GEMM+split -> knn -> refine ========================
    const int bb = b - 16;                 // 0..255
    {   // ---------------- GEMM + BN stats (rows bb*256..+255), 512 threads
        float* wt = smem;                  // [128][68] W^T
        float* fl = smem + 8704;           // [64][68]
#pragma unroll
        for (int it = 0; it < 4; it++) {
            int lid = t + 512 * it;
            int k = lid >> 5, c4 = lid & 31;
            float4 v = *(const float4*)&W[k * FOUT + c4 * 4];
            wt[(c4 * 4 + 0) * 68 + k] = v.x;
            wt[(c4 * 4 + 1) * 68 + k] = v.y;
            wt[(c4 * 4 + 2) * 68 + k] = v.z;
            wt[(c4 * 4 + 3) * 68 + k] = v.w;
        }
        const int rowbase0 = bb * 256;
        const int rg = t >> 5, cg = t & 31;
        float sums[4] = {0, 0, 0, 0};
        float sqs[4]  = {0, 0, 0, 0};
        for (int sub = 0; sub < 4; sub++) {
            const int rowbase = rowbase0 + sub * 64;
            __syncthreads();
#pragma unroll
            for (int it = 0; it < 2; it++) {
                int lid = t + 512 * it;
                int r = lid >> 4, f4 = lid & 15;
                float4 v = *(const float4*)&feat[(size_t)(rowbase + r) * FIN + f4 * 4];
                *(float4*)&fl[r * 68 + f4 * 4] = v;
            }
            __syncthreads();
            float acc[4][4];
#pragma unroll
            for (int i = 0; i < 4; i++)
#pragma unroll
                for (int j = 0; j < 4; j++) acc[i][j] = 0.f;
#pragma unroll 2
            for (int k4 = 0; k4 < 16; k4++) {
                float4 f4v[4], w4v[4];
#pragma unroll
                for (int i = 0; i < 4; i++) f4v[i] = *(float4*)&fl[(rg * 4 + i) * 68 + k4 * 4];
#pragma unroll
                for (int j = 0; j < 4; j++) w4v[j] = *(float4*)&wt[(cg + 32 * j) * 68 + k4 * 4];
#pragma unroll
                for (int i = 0; i < 4; i++)
#pragma unroll
                    for (int j = 0; j < 4; j++) {
                        acc[i][j] = fmaf(f4v[i].x, w4v[j].x, acc[i][j]);
                        acc[i][j] = fmaf(f4v[i].y, w4v[j].y, acc[i][j]);
                        acc[i][j] = fmaf(f4v[i].z, w4v[j].z, acc[i][j]);
                        acc[i][j] = fmaf(f4v[i].w, w4v[j].w, acc[i][j]);
                    }
            }
#pragma unroll
            for (int j = 0; j < 4; j++) {
                int c = cg + 32 * j;
                float bc = bias[c];
#pragma unroll
                for (int i = 0; i < 4; i++) {
                    float h = acc[i][j] + bc;
                    sums[j] += h; sqs[j] += h * h;
                    hout[(size_t)(rowbase + rg * 4 + i) * FOUT + c] = __float2bfloat16(h);
                }
            }
        }
        __syncthreads();
        float* suml = fl;
        float* sql  = wt;
#pragma unroll
        for (int j = 0; j < 4; j++) {
            suml[rg * FOUT + cg + 32 * j] = sums[j];
            sql[rg * FOUT + cg + 32 * j]  = sqs[j];
        }
        __syncthreads();
        if (t < FOUT) {
            float S = 0.f, Q = 0.f;
#pragma unroll
            for (int r = 0; r < 16; r++) { S += suml[r * FOUT + t]; Q += sql[r * FOUT + t]; }
            atomicAdd(&gsum[t], S);
            atomicAdd(&gsq[t], Q);
        }
        // ---------------- xnorm + bf16 hi/lo split for the same 256 rows (t<256)
        if (t < 256) {
            int r = rowbase0 + t;
            const float4* fr = (const float4*)&feat[(size_t)r * FIN];
            unsigned short hrow[64], lrow[64];
            float s = 0.f;
#pragma unroll
            for (int i = 0; i < 16; i++) {
                float4 v = fr[i];
                s += v.x * v.x + v.y * v.y + v.z * v.z + v.w * v.w;
                float vv[4] = {v.x, v.y, v.z, v.w};
#pragma unroll
                for (int j = 0; j < 4; j++) {
                    unsigned short h = bf16_rn(vv[j]);
                    float hf = __uint_as_float((unsigned)h << 16);
                    hrow[4 * i + j] = h;
                    lrow[4 * i + j] = bf16_rn(vv[j] - hf);
                }
            }
            xnorm[r] = s;
#pragma unroll
            for (int i = 0; i < 8; i++) {
                short8 hv, lv;
#pragma unroll
                for (int j = 0; j < 8; j++) { hv[j] = (short)hrow[8 * i + j]; lv[j] = (short)lrow[8 * i + j]; }
                *(short8*)&Xhi[(size_t)r * 64 + 8 * i] = hv;
                *(short8*)&Xlo[(size_t)r * 64 + 8 * i] = lv;
            }
        }
        __threadfence();
        __syncthreads();
        if (t == 0) {
            atomicAdd(&splitc[bb >> 4], 1);
            ((int*)smem)[0] = atomicAdd(gemmc, 1);
        }
        __syncthreads();
        if (((int*)smem)[0] == 255) {   // last GEMM block finalizes BN
            if (t < FOUT) {
                float S = __hip_atomic_load(&gsum[t], __ATOMIC_RELAXED, __HIP_MEMORY_SCOPE_AGENT);
                float Q = __hip_atomic_load(&gsq[t], __ATOMIC_RELAXED, __HIP_MEMORY_SCOPE_AGENT);
                float mean = S * (1.0f / NN);
                float var  = Q * (1.0f / NN) - mean * mean;
                float sc = rsqrtf(var + 1e-5f) * gamma[t];
                acoef[t] = sc;
                ccoef[t] = beta[t] - mean * sc;
            }
            __threadfence();
            __syncthreads();
            if (t == 0)
                __hip_atomic_store(bnflag, 1, __ATOMIC_RELEASE, __HIP_MEMORY_SCOPE_AGENT);
        }
        __syncthreads();
    }

    const int cloud = bb & 15, qg = bb >> 4;
    const int cbase = cloud * NP;

    // ---------------- wait: cloud's split done + this qgroup's FPS indices published
    if (t == 0) {
        while (__hip_atomic_load(&splitc[cloud], __ATOMIC_ACQUIRE, __HIP_MEMORY_SCOPE_AGENT) < 16)
            __builtin_amdgcn_s_sleep(32);
        while (__hip_atomic_load(&fps_flag[cloud * 16 + qg], __ATOMIC_ACQUIRE, __HIP_MEMORY_SCOPE_AGENT) == 0)
            __builtin_amdgcn_s_sleep(32);
    }
    __syncthreads();

    {   // ---------------- knn filter (R8-validated two-phase threshold), 8 waves
        float* TL = smem;                              // [8][16][32]
        float* TQ = smem + 4096;                       // [8][16]
        int*   cnt = (int*)(smem + 4224);              // [8][16]
        unsigned short* kbuf = (unsigned short*)(smem + 4352);  // [8][16][64]
        const int wave = t >> 6, lane = t & 63;
        const int quad = lane >> 4, col = lane & 15;
        const int half = wave >> 2;
        const int qloc = qg * 64 + (wave & 3) * 16;
        const int qrow = __hip_atomic_load(&fps_idx[cloud * MS + qloc + col],
                                           __ATOMIC_RELAXED, __HIP_MEMORY_SCOPE_AGENT);
        const unsigned short* Qh = Xhi + (size_t)(cbase + qrow) * 64;
        const unsigned short* Ql = Xlo + (size_t)(cbase + qrow) * 64;
        short8 Ah0 = *(const short8*)(Qh + quad * 8);
        short8 Ah1 = *(const short8*)(Qh + 32 + quad * 8);
        short8 Al0 = *(const short8*)(Ql + quad * 8);
        short8 Al1 = *(const short8*)(Ql + 32 + quad * 8);

        const int pstart = half * 2048;
        float mA[4] = {INFINITY, INFINITY, INFINITY, INFINITY};
        float mB[4] = {INFINITY, INFINITY, INFINITY, INFINITY};
        for (int tile = 0; tile < 128; tile++) {
            const int prow = cbase + pstart + tile * 16 + col;
            const unsigned short* Bh = Xhi + (size_t)prow * 64;
            const unsigned short* Bl = Xlo + (size_t)prow * 64;
            short8 bh0 = *(const short8*)(Bh + quad * 8);
            short8 bh1 = *(const short8*)(Bh + 32 + quad * 8);
            short8 bl0 = *(const short8*)(Bl + quad * 8);
            short8 bl1 = *(const short8*)(Bl + 32 + quad * 8);
            f32x4 acc = {0.f, 0.f, 0.f, 0.f};
            acc = __builtin_amdgcn_mfma_f32_16x16x32_bf16(Ah0, bh0, acc, 0, 0, 0);
            acc = __builtin_amdgcn_mfma_f32_16x16x32_bf16(Ah1, bh1, acc, 0, 0, 0);
            acc = __builtin_amdgcn_mfma_f32_16x16x32_bf16(Al0, bh0, acc, 0, 0, 0);
            acc = __builtin_amdgcn_mfma_f32_16x16x32_bf16(Al1, bh1, acc, 0, 0, 0);
            acc = __builtin_amdgcn_mfma_f32_16x16x32_bf16(Ah0, bl0, acc, 0, 0, 0);
            acc = __builtin_amdgcn_mfma_f32_16x16x32_bf16(Ah1, bl1, acc, 0, 0, 0);
            float xnv = xnorm[prow];
#pragma unroll
            for (int r = 0; r < 4; r++) {
                float s = fmaf(-2.0f, acc[r], xnv);
                float mx = fmaxf(mA[r], s);
                mA[r] = fminf(mA[r], s);
                mB[r] = fminf(mB[r], mx);
            }
        }
#pragma unroll
        for (int r = 0; r < 4; r++) {
            TL[(wave * 16 + quad * 4 + r) * 32 + col * 2 + 0] = mA[r];
            TL[(wave * 16 + quad * 4 + r) * 32 + col * 2 + 1] = mB[r];
        }
        if (lane < 16) cnt[wave * 16 + lane] = 0;
        {
            const int q = lane >> 2, j0 = (lane & 3) * 8;
            float v[32];
#pragma unroll
            for (int j = 0; j < 32; j++) v[j] = TL[(wave * 16 + q) * 32 + j];
#pragma unroll
            for (int u = 0; u < 8; u++) {
                float vj = v[j0 + u];
                int jj = j0 + u, rank = 0;
#pragma unroll
                for (int k = 0; k < 32; k++)
                    rank += (v[k] < vj || (v[k] == vj && k < jj)) ? 1 : 0;
                if (rank == 15) TQ[wave * 16 + q] = vj;
            }
        }
        float T0 = TQ[wave * 16 + quad * 4 + 0] + KNN_MARGIN;
        float T1 = TQ[wave * 16 + quad * 4 + 1] + KNN_MARGIN;
        float T2 = TQ[wave * 16 + quad * 4 + 2] + KNN_MARGIN;
        float T3 = TQ[wave * 16 + quad * 4 + 3] + KNN_MARGIN;
        for (int tile = 0; tile < 128; tile++) {
            const int pidx = pstart + tile * 16 + col;
            const int prow = cbase + pidx;
            const unsigned short* Bh = Xhi + (size_t)prow * 64;
            const unsigned short* Bl = Xlo + (size_t)prow * 64;
            short8 bh0 = *(const short8*)(Bh + quad * 8);
            short8 bh1 = *(const short8*)(Bh + 32 + quad * 8);
            short8 bl0 = *(const short8*)(Bl + quad * 8);
            short8 bl1 = *(const short8*)(Bl + 32 + quad * 8);
            f32x4 acc = {0.f, 0.f, 0.f, 0.f};
            acc = __builtin_amdgcn_mfma_f32_16x16x32_bf16(Ah0, bh0, acc, 0, 0, 0);
            acc = __builtin_amdgcn_mfma_f32_16x16x32_bf16(Ah1, bh1, acc, 0, 0, 0);
            acc = __builtin_amdgcn_mfma_f32_16x16x32_bf16(Al0, bh0, acc, 0, 0, 0);
            acc = __builtin_amdgcn_mfma_f32_16x16x32_bf16(Al1, bh1, acc, 0, 0, 0);
            acc = __builtin_amdgcn_mfma_f32_16x16x32_bf16(Ah0, bl0, acc, 0, 0, 0);
            acc = __builtin_amdgcn_mfma_f32_16x16x32_bf16(Ah1, bl1, acc, 0, 0, 0);
            float xnv = xnorm[prow];
            float s0 = fmaf(-2.0f, acc[0], xnv);
            float s1 = fmaf(-2.0f, acc[1], xnv);
            float s2 = fmaf(-2.0f, acc[2], xnv);
            float s3 = fmaf(-2.0f, acc[3], xnv);
            if (s0 <= T0) { int p = atomicAdd(&cnt[wave * 16 + quad * 4 + 0], 1); if (p < 64) kbuf[(wave * 16 + quad * 4 + 0) * 64 + p] = (unsigned short)pidx; }
            if (s1 <= T1) { int p = atomicAdd(&cnt[wave * 16 + quad * 4 + 1], 1); if (p < 64) kbuf[(wave * 16 + quad * 4 + 1) * 64 + p] = (unsigned short)pidx; }
            if (s2 <= T2) { int p = atomicAdd(&cnt[wave * 16 + quad * 4 + 2], 1); if (p < 64) kbuf[(wave * 16 + quad * 4 + 2) * 64 + p] = (unsigned short)pidx; }
            if (s3 <= T3) { int p = atomicAdd(&cnt[wave * 16 + quad * 4 + 3], 1); if (p < 64) kbuf[(wave * 16 + quad * 4 + 3) * 64 + p] = (unsigned short)pidx; }
        }
#pragma unroll
        for (int q = 0; q < 16; q++) {
            int n = cnt[wave * 16 + q];
            unsigned short val = (lane < n) ? kbuf[(wave * 16 + q) * 64 + lane] : (unsigned short)0xFFFF;
            cand[(size_t)(cloud * MS + qloc + q) * 128 + half * 64 + lane] = val;
        }
    }
    __threadfence();
    __syncthreads();
    if (t == 0) atomicAdd(&knnc[cloud], 1);

    // ---------------- wait: all knn of this cloud done (Xlo-overwrite safety) + BN coefs
    if (t == 0) {
        while (__hip_atomic_load(&knnc[cloud], __ATOMIC_ACQUIRE, __HIP_MEMORY_SCOPE_AGENT) < 16)
            __builtin_amdgcn_s_sleep(32);
        while (__hip_atomic_load(bnflag, __ATOMIC_ACQUIRE, __HIP_MEMORY_SCOPE_AGENT) == 0)
            __builtin_amdgcn_s_sleep(32);
    }
    __syncthreads();

    {   // ---------------- refine: exact fp32 top-16 + gather/BN/ReLU/maxpool, 2 q at a time
        float* qlds = smem;               // [2][64]
        float* cD   = smem + 128;         // [2][128]
        int*   cI   = (int*)(smem + 384); // [2][128]
        int*   fIdx = (int*)(smem + 640); // [2][16]
        float* cf   = smem + 672;         // [256]
        if (t < 256) cf[t] = (t < 128) ? acoef[t] : ccoef[t - 128];
        __syncthreads();
        const int sb = t >> 8, tt = t & 255;
        const __hip_bfloat16* hb = hout + (size_t)cbase * FOUT;
        for (int it = 0; it < 32; it++) {
            const int q = cloud * MS + qg * 64 + it * 2 + sb;
            if (tt < 16) {
                int qr = __hip_atomic_load(&fps_idx[q], __ATOMIC_RELAXED, __HIP_MEMORY_SCOPE_AGENT);
                float4 v = ((const float4*)(feat + (size_t)(cbase + qr) * FIN))[tt];
                *(float4*)&qlds[sb * 64 + tt * 4] = v;
            }
            __syncthreads();
            const int c = tt >> 1, jh = tt & 1;
            const unsigned short cs = cand[(size_t)q * 128 + c];
            const bool valid = (cs != 0xFFFF);
            const int cidx = valid ? (int)cs : 0;
            const float4* xr = (const float4*)(feat + (size_t)(cbase + cidx) * FIN) + jh * 8;
            float a0 = 0.f, a1 = 0.f, a2 = 0.f, a3 = 0.f;
#pragma unroll
            for (int i = 0; i < 8; i++) {
                float4 x4 = xr[i];
                a0 = fmaf(qlds[sb * 64 + jh * 32 + 4 * i + 0], x4.x, a0);
                a1 = fmaf(qlds[sb * 64 + jh * 32 + 4 * i + 1], x4.y, a1);
                a2 = fmaf(qlds[sb * 64 + jh * 32 + 4 * i + 2], x4.z, a2);
                a3 = fmaf(qlds[sb * 64 + jh * 32 + 4 * i + 3], x4.w, a3);
            }
            float a = (a0 + a1) + (a2 + a3);
            a += __shfl_xor(a, 1);
            if (jh == 0) {
                cD[sb * 128 + c] = valid ? fmaf(-2.0f, a, xnorm[cbase + cidx]) : INFINITY;
                cI[sb * 128 + c] = valid ? cidx : (65536 + c);
            }
            __syncthreads();
            if (tt < 128) {
                float dv = cD[sb * 128 + tt]; int iv = cI[sb * 128 + tt]; int rank = 0;
#pragma unroll 8
                for (int j = 0; j < 128; j++) {
                    float dj = cD[sb * 128 + j]; int ij = cI[sb * 128 + j];
                    rank += (dj < dv || (dj == dv && ij < iv)) ? 1 : 0;
                }
                if (rank < 16) fIdx[sb * 16 + rank] = iv;
            }
            __syncthreads();
            if (tt < 128) {
                const float ac = cf[tt], cc = cf[128 + tt];
                float mx = -INFINITY;
#pragma unroll
                for (int k = 0; k < 16; k++) {
                    int row = fIdx[sb * 16 + k];
                    float hv = __bfloat162float(hb[(size_t)row * FOUT + tt]);
                    mx = fmaxf(mx, fmaxf(fmaf(ac, hv, cc), 0.f));
                }
                out_feat[(size_t)q * FOUT + tt] = mx;
            }
            __syncthreads();
        }
    }
}

// ---------------------------------------------------------------- launch
extern "C" void kernel_launch(void* const* d_in, const int* in_sizes, int n_in,
                              void* d_out, int out_size, void* d_ws, size_t ws_size,
                              hipStream_t stream) {
    (void)in_sizes; (void)n_in; (void)out_size; (void)ws_size;
    const float* position = (const float*)d_in[0];
    const float* features = (const float*)d_in[1];
    const float* W        = (const float*)d_in[3];
    const float* bias     = (const float*)d_in[4];
    const float* gamma    = (const float*)d_in[5];
    const float* beta     = (const float*)d_in[6];
    float* out = (float*)d_out;

    char* ws = (char*)d_ws;
    int*   fps_idx = (int*)ws;                               // 64 KB
    float* gsum    = (float*)(ws + 65536);                   // 512 B
    float* gsq     = (float*)(ws + 66048);                   // 512 B
    int*   flags   = (int*)(ws + 66560);                     // 2 KB (zeroed)
    float* acoef   = (float*)(ws + 68608);                   // 512 B
    float* ccoef   = (float*)(ws + 69120);                   // 512 B
    float* xnorm   = (float*)(ws + 69632);                   // 256 KB -> 331776
    unsigned short* cand = (unsigned short*)(ws + 331776);   // 4 MB   -> 4526080
    unsigned short* Xhi  = (unsigned short*)(ws + 4526080);  // 8 MB   -> 12914688
    __hip_bfloat16* hbuf = (__hip_bfloat16*)(ws + 12914688); // 16 MB  -> ~29.7 MB

    float* out_feat  = out;                 // [16384][128]
    float* out_pos   = out + 2097152;       // [16384][3]
    float* out_batch = out + 2146304;       // [16384]
    // Xlo lives in the out_feat region (8 MB exact fit); refine overwrites it only after
    // knn_done[cloud]==16 (all readers of that cloud's Xlo finished).
    unsigned short* Xlo = (unsigned short*)out;

    hipMemsetAsync(ws + 65536, 0, 3072, stream);  // zero gsum+gsq+flags
    mega_kernel<<<272, 512, 0, stream>>>(position, features, W, bias, gamma, beta,
                                         fps_idx, xnorm, Xhi, Xlo, hbuf, gsum, gsq,
                                         acoef, ccoef, cand, flags,
                                         out_feat, out_pos, out_batch);
}